// Round 10
// baseline (2645.420 us; speedup 1.0000x reference)
//
#include <hip/hip_runtime.h>
#include <hip/hip_bf16.h>

#define DEV __device__ __forceinline__

constexpr int B_ = 256;   // batch
constexpr int T_ = 512;   // time
constexpr int H_ = 128;   // GRU units
constexpr int K_ = 256;   // input dim per layer (D = 2H = 256 for all layers)
constexpr int G_ = 384;   // 3H
constexpr int M_ = B_ * T_;
constexpr int LDSROW = 72;  // ushorts per LDS tile row (64 data + 8 pad)
constexpr int ULS = 76;     // floats per Ulds row (64 data + 12 pad, 16B-mult)

using bf16 = __hip_bfloat16;
typedef short bf16x8 __attribute__((ext_vector_type(8)));
typedef float f32x4 __attribute__((ext_vector_type(4)));
typedef float f32x2 __attribute__((ext_vector_type(2)));

DEV float tof(float x) { return x; }
DEV float tof(bf16 x) { return __bfloat162float(x); }
DEV void stor(float* p, float v) { *p = v; }
DEV void stor(bf16* p, float v) { *p = __float2bfloat16(v); }

// float -> bf16 bits, round-to-nearest-even
DEV unsigned short f2bs(float f) {
  union { float f; unsigned u; } v;
  v.f = f;
  unsigned r = (v.u + 0x7FFFu + ((v.u >> 16) & 1u)) >> 16;
  return (unsigned short)r;
}
DEV float bs2f(unsigned short s) {
  union { unsigned u; float f; } v;
  v.u = ((unsigned)s) << 16;
  return v.f;
}

DEV float fsigmoid(float x) { return 1.f / (1.f + __expf(-x)); }
DEV float ftanh(float x) {
  x = fminf(20.f, fmaxf(-20.f, x));
  float e = __expf(-2.f * x);
  return (1.f - e) / (1.f + e);
}

// Barrier draining only LDS traffic (lgkmcnt), not global loads/stores.
DEV void barrier_lds() {
  asm volatile("s_waitcnt lgkmcnt(0)\n\ts_barrier" ::: "memory");
}

DEV f32x4 mfma16(bf16x8 a, bf16x8 b, f32x4 c) {
  return __builtin_amdgcn_mfma_f32_16x16x32_bf16(a, b, c, 0, 0, 0);
}

// Butterfly sum over 8-lane groups on the VALU pipe (DPP): masks {1,2,7} =
// quad_perm[1,0,3,2]=0xB1, quad_perm[2,3,0,1]=0x4E, row_half_mirror=0x141.
DEV float dpp_red8(float x) {
  int t;
  t = __builtin_amdgcn_update_dpp(0, __float_as_int(x), 0xB1, 0xF, 0xF, true);
  x += __int_as_float(t);
  t = __builtin_amdgcn_update_dpp(0, __float_as_int(x), 0x4E, 0xF, 0xF, true);
  x += __int_as_float(t);
  t = __builtin_amdgcn_update_dpp(0, __float_as_int(x), 0x141, 0xF, 0xF, true);
  x += __int_as_float(t);
  return x;
}

// ---------------------------------------------------------------------------
// convX: split fp32 x[M,256] into bf16 hi/lo arrays (layer-0 GEMM input).
// ---------------------------------------------------------------------------
__global__ __launch_bounds__(256) void convX_kernel(
    const float* __restrict__ x, ushort* __restrict__ hiA,
    ushort* __restrict__ loA) {
  const int n4 = M_ * K_ / 4;
  for (int idx = blockIdx.x * blockDim.x + threadIdx.x; idx < n4;
       idx += gridDim.x * blockDim.x) {
    float4 v = ((const float4*)x)[idx];
    ushort4 h, l;
    h.x = f2bs(v.x); l.x = f2bs(v.x - bs2f(h.x));
    h.y = f2bs(v.y); l.y = f2bs(v.y - bs2f(h.y));
    h.z = f2bs(v.z); l.z = f2bs(v.z - bs2f(h.z));
    h.w = f2bs(v.w); l.w = f2bs(v.w - bs2f(h.w));
    ((ushort4*)hiA)[idx] = h;
    ((ushort4*)loA)[idx] = l;
  }
}

// ---------------------------------------------------------------------------
// convW: W[dir][256][384] fp32 -> W^T hi/lo bf16 [768 ncol][256 k].
// ---------------------------------------------------------------------------
__global__ __launch_bounds__(256) void convW_kernel(
    const float* __restrict__ W, ushort* __restrict__ WhiT,
    ushort* __restrict__ WloT) {
  const int ncol = blockIdx.x;           // 0..767
  const int dir = ncol / G_, j = ncol % G_;
  const int k = threadIdx.x;             // 0..255
  const float f = W[((size_t)dir * K_ + k) * G_ + j];
  const unsigned short hi = f2bs(f);
  WhiT[(size_t)ncol * K_ + k] = hi;
  WloT[(size_t)ncol * K_ + k] = f2bs(f - bs2f(hi));
}

// ---------------------------------------------------------------------------
// convU: U[dir][128][384] fp32 -> UT[dir][384 col][128 k] (transposed).
// Gives the rec kernel contiguous per-column k-runs (dwordx4 loads + LDS
// staging without strided gathers).
// ---------------------------------------------------------------------------
__global__ __launch_bounds__(128) void convU_kernel(
    const float* __restrict__ U, float* __restrict__ UT) {
  const int col = blockIdx.x;   // 0..383
  const int dir = blockIdx.y;
  const int k = threadIdx.x;    // 0..127
  UT[((size_t)dir * G_ + col) * H_ + k] =
      U[(size_t)dir * H_ * G_ + (size_t)k * G_ + col];
}

// ---------------------------------------------------------------------------
// gemm3: C[M,768] = A[M,256] @ W^T' + bias, bf16 hi/lo 3-term split MFMA.
// ---------------------------------------------------------------------------
template <typename XT>
__global__ __launch_bounds__(256, 2) void gemm3_kernel(
    const ushort* __restrict__ Ahi, const ushort* __restrict__ Alo,
    const ushort* __restrict__ WhiT, const ushort* __restrict__ WloT,
    const float* __restrict__ bbias, XT* __restrict__ xp) {
  const int m0 = blockIdx.x * 128;
  const int n0 = blockIdx.y * 128;
  const int tid = threadIdx.x;
  const int w = tid >> 6, lane = tid & 63;
  const int wm = w >> 1, wn = w & 1;
  const int col = lane & 15, quad = lane >> 4;

  __shared__ __align__(16) ushort AH[128 * LDSROW];
  __shared__ __align__(16) ushort AL[128 * LDSROW];
  __shared__ __align__(16) ushort BH[128 * LDSROW];
  __shared__ __align__(16) ushort BL[128 * LDSROW];

  f32x4 acc[4][4];
#pragma unroll
  for (int i = 0; i < 4; ++i)
#pragma unroll
    for (int n = 0; n < 4; ++n) acc[i][n] = (f32x4){0.f, 0.f, 0.f, 0.f};

  const ushort* gsrc = (w == 0) ? Ahi : (w == 1) ? Alo : (w == 2) ? WhiT : WloT;
  ushort* lds = (w == 0) ? AH : (w == 1) ? AL : (w == 2) ? BH : BL;
  const int rbase = (w < 2) ? m0 : n0;

  for (int kb = 0; kb < K_; kb += 64) {
#pragma unroll
    for (int q = 0; q < 16; ++q) {
      const int slot = q * 64 + lane;
      const int r = slot >> 3, s = slot & 7;
      bf16x8 v = *(const bf16x8*)(gsrc + (size_t)(rbase + r) * K_ + kb + s * 8);
      *(bf16x8*)&lds[r * LDSROW + s * 8] = v;
    }
    __syncthreads();
#pragma unroll
    for (int z = 0; z < 2; ++z) {
      const int cc8 = (z * 4 + quad) * 8;
      bf16x8 ah[4], al[4], bh[4], bl[4];
#pragma unroll
      for (int i = 0; i < 4; ++i) {
        const int row = wm * 64 + i * 16 + col;
        ah[i] = *(const bf16x8*)&AH[row * LDSROW + cc8];
        al[i] = *(const bf16x8*)&AL[row * LDSROW + cc8];
      }
#pragma unroll
      for (int n = 0; n < 4; ++n) {
        const int row = wn * 64 + n * 16 + col;
        bh[n] = *(const bf16x8*)&BH[row * LDSROW + cc8];
        bl[n] = *(const bf16x8*)&BL[row * LDSROW + cc8];
      }
#pragma unroll
      for (int i = 0; i < 4; ++i)
#pragma unroll
        for (int n = 0; n < 4; ++n) {
          acc[i][n] = mfma16(ah[i], bh[n], acc[i][n]);
          acc[i][n] = mfma16(al[i], bh[n], acc[i][n]);
          acc[i][n] = mfma16(ah[i], bl[n], acc[i][n]);
        }
    }
    __syncthreads();
  }

  const int dir = (n0 >= G_) ? 1 : 0;
#pragma unroll
  for (int n = 0; n < 4; ++n) {
    const int ncol = n0 + wn * 64 + n * 16 + col;
    const int g = ncol - dir * G_;
    const float bv = bbias[dir * 2 * G_ + g];
#pragma unroll
    for (int i = 0; i < 4; ++i) {
      const int mb = m0 + wm * 64 + i * 16 + quad * 4;
#pragma unroll
      for (int r = 0; r < 4; ++r) {
        const int m = mb + r;
        const int bb = m >> 9;          // T_ = 512
        const int t = m & (T_ - 1);
        stor(xp + ((size_t)(dir * T_ + t) * B_ + bb) * G_ + g,
             acc[i][n][r] + bv);
      }
    }
  }
}

// ---------------------------------------------------------------------------
// Recurrence. Grid (128, 2): 2 batch rows/block, 768 threads.
// Thread (cg=tid>>3, kc=tid&7) computes 4 columns [4cg,4cg+4) over k-chunks
// {32i+4kc..+4 : i<4}. KEY CHANGE (R10): U's k<64 half lives in LDS (114 KB,
// staged once from UT), U's k>=64 half (32 floats) in named registers.
// The ~121 KB LDS footprint forces occupancy to 1 block = 3 waves/SIMD, so
// the compiler's VGPR budget is ~168 and the register half actually sticks
// (R4-R9: with 4 KB LDS the scheduler targeted 8 waves -> 64-VGPR budget ->
// U was reloaded from L2 every step = the real bottleneck).
// ---------------------------------------------------------------------------
template <typename XT, bool LAST>
__global__ __launch_bounds__(768, 3) void rec_kernel(
    const XT* __restrict__ xp, const float* UTbase,
    const float* __restrict__ bbase, ushort* __restrict__ seqH,
    ushort* __restrict__ seqL, float* __restrict__ fin) {
  const int dir = blockIdx.y;
  const float* UT = UTbase + (size_t)dir * G_ * H_;   // [col][128]
  const float* bh = bbase + dir * (2 * G_) + G_;
  const int b0 = blockIdx.x * 2;
  const int tid = threadIdx.x;
  const int kc = tid & 7;        // k-chunk selector
  const int cg = tid >> 3;       // column group 0..95
  const int kc4 = kc * 4;
  const int c0 = cg * 4;

  __shared__ __align__(16) float hbuf[2][H_];
  __shared__ float rec_s[2][G_];
  __shared__ __align__(16) float Ulds[G_ * ULS];  // U k<64 half, [col][76]

  // stage U k<64 half: 384 cols x 16 float4 chunks = 6144 chunks, 8/thread
#pragma unroll
  for (int q = 0; q < 8; ++q) {
    const int id = q * 768 + tid;
    const int row = id >> 4, c16 = id & 15;
    *(float4*)&Ulds[row * ULS + c16 * 4] =
        *(const float4*)&UT[(size_t)row * H_ + c16 * 4];
  }

  // register half: k in [64,128), 32 floats as 16 named f32x2
  f32x2 r0a, r0b, r1a, r1b, r2a, r2b, r3a, r3b;   // i=2 (k = 64+kc4..)
  f32x2 s0a, s0b, s1a, s1b, s2a, s2b, s3a, s3b;   // i=3 (k = 96+kc4..)
#define LDR(c, base, ra, rb)                                         \
  {                                                                  \
    float4 t_ = *(const float4*)&UT[(size_t)(c0 + (c)) * H_ + (base) + kc4]; \
    ra = (f32x2){t_.x, t_.y};                                        \
    rb = (f32x2){t_.z, t_.w};                                        \
  }
  LDR(0, 64, r0a, r0b) LDR(1, 64, r1a, r1b)
  LDR(2, 64, r2a, r2b) LDR(3, 64, r3a, r3b)
  LDR(0, 96, s0a, s0b) LDR(1, 96, s1a, s1b)
  LDR(2, 96, s2a, s2b) LDR(3, 96, s3a, s3b)
#undef LDR

  const int wc = kc & 3, wr = kc >> 2;     // this thread's rec_s write slot
  const float bmine = bh[c0 + wc];

  const int grow = tid >> 7;        // gate-phase row (tid < 256)
  const int gu = tid & (H_ - 1);    // gate-phase unit
  const bool gateT = tid < 2 * H_;

  if (gateT) hbuf[grow][gu] = 0.f;

  const XT* xbase = xp + (size_t)(dir * T_) * B_ * G_;

  XT xzc{}, xrc{}, xhc{};
  {
    const int t0 = dir ? (T_ - 1) : 0;
    if (gateT) {
      const XT* xr_ = xbase + ((size_t)t0 * B_ + b0 + grow) * G_ + gu;
      xzc = xr_[0];
      xrc = xr_[H_];
      xhc = xr_[2 * H_];
    }
  }
  barrier_lds();

  for (int it = 0; it < T_; ++it) {
    const int t = dir ? (T_ - 1 - it) : it;

    // --- prefetch xp for step it+1 (hidden under the dot phase) ---
    XT xzn = xzc, xrn = xrc, xhn = xhc;
    if (gateT && (it + 1 < T_)) {
      const int tn = dir ? (t - 1) : (t + 1);
      const XT* xr_ = xbase + ((size_t)tn * B_ + b0 + grow) * G_ + gu;
      xzn = xr_[0];
      xrn = xr_[H_];
      xhn = xr_[2 * H_];
    }

    // --- dot phase ---
    f32x2 a00 = {0.f, 0.f}, a01 = {0.f, 0.f}, a02 = {0.f, 0.f}, a03 = {0.f, 0.f};
    f32x2 a10 = {0.f, 0.f}, a11 = {0.f, 0.f}, a12 = {0.f, 0.f}, a13 = {0.f, 0.f};

    // i = 0,1 : U from LDS
#pragma unroll
    for (int i = 0; i < 2; ++i) {
      float4 h0 = *(const float4*)&hbuf[0][i * 32 + kc4];
      float4 h1 = *(const float4*)&hbuf[1][i * 32 + kc4];
      f32x2 h0a = {h0.x, h0.y}, h0b = {h0.z, h0.w};
      f32x2 h1a = {h1.x, h1.y}, h1b = {h1.z, h1.w};
      float4 u0 = *(const float4*)&Ulds[(c0 + 0) * ULS + i * 32 + kc4];
      float4 u1 = *(const float4*)&Ulds[(c0 + 1) * ULS + i * 32 + kc4];
      float4 u2 = *(const float4*)&Ulds[(c0 + 2) * ULS + i * 32 + kc4];
      float4 u3 = *(const float4*)&Ulds[(c0 + 3) * ULS + i * 32 + kc4];
      f32x2 u0a = {u0.x, u0.y}, u0b = {u0.z, u0.w};
      f32x2 u1a = {u1.x, u1.y}, u1b = {u1.z, u1.w};
      f32x2 u2a = {u2.x, u2.y}, u2b = {u2.z, u2.w};
      f32x2 u3a = {u3.x, u3.y}, u3b = {u3.z, u3.w};
      a00 = __builtin_elementwise_fma(h0a, u0a, a00);
      a00 = __builtin_elementwise_fma(h0b, u0b, a00);
      a01 = __builtin_elementwise_fma(h0a, u1a, a01);
      a01 = __builtin_elementwise_fma(h0b, u1b, a01);
      a02 = __builtin_elementwise_fma(h0a, u2a, a02);
      a02 = __builtin_elementwise_fma(h0b, u2b, a02);
      a03 = __builtin_elementwise_fma(h0a, u3a, a03);
      a03 = __builtin_elementwise_fma(h0b, u3b, a03);
      a10 = __builtin_elementwise_fma(h1a, u0a, a10);
      a10 = __builtin_elementwise_fma(h1b, u0b, a10);
      a11 = __builtin_elementwise_fma(h1a, u1a, a11);
      a11 = __builtin_elementwise_fma(h1b, u1b, a11);
      a12 = __builtin_elementwise_fma(h1a, u2a, a12);
      a12 = __builtin_elementwise_fma(h1b, u2b, a12);
      a13 = __builtin_elementwise_fma(h1a, u3a, a13);
      a13 = __builtin_elementwise_fma(h1b, u3b, a13);
    }
    // i = 2 : U from registers (r*)
    {
      float4 h0 = *(const float4*)&hbuf[0][64 + kc4];
      float4 h1 = *(const float4*)&hbuf[1][64 + kc4];
      f32x2 h0a = {h0.x, h0.y}, h0b = {h0.z, h0.w};
      f32x2 h1a = {h1.x, h1.y}, h1b = {h1.z, h1.w};
      a00 = __builtin_elementwise_fma(h0a, r0a, a00);
      a00 = __builtin_elementwise_fma(h0b, r0b, a00);
      a01 = __builtin_elementwise_fma(h0a, r1a, a01);
      a01 = __builtin_elementwise_fma(h0b, r1b, a01);
      a02 = __builtin_elementwise_fma(h0a, r2a, a02);
      a02 = __builtin_elementwise_fma(h0b, r2b, a02);
      a03 = __builtin_elementwise_fma(h0a, r3a, a03);
      a03 = __builtin_elementwise_fma(h0b, r3b, a03);
      a10 = __builtin_elementwise_fma(h1a, r0a, a10);
      a10 = __builtin_elementwise_fma(h1b, r0b, a10);
      a11 = __builtin_elementwise_fma(h1a, r1a, a11);
      a11 = __builtin_elementwise_fma(h1b, r1b, a11);
      a12 = __builtin_elementwise_fma(h1a, r2a, a12);
      a12 = __builtin_elementwise_fma(h1b, r2b, a12);
      a13 = __builtin_elementwise_fma(h1a, r3a, a13);
      a13 = __builtin_elementwise_fma(h1b, r3b, a13);
    }
    // i = 3 : U from registers (s*)
    {
      float4 h0 = *(const float4*)&hbuf[0][96 + kc4];
      float4 h1 = *(const float4*)&hbuf[1][96 + kc4];
      f32x2 h0a = {h0.x, h0.y}, h0b = {h0.z, h0.w};
      f32x2 h1a = {h1.x, h1.y}, h1b = {h1.z, h1.w};
      a00 = __builtin_elementwise_fma(h0a, s0a, a00);
      a00 = __builtin_elementwise_fma(h0b, s0b, a00);
      a01 = __builtin_elementwise_fma(h0a, s1a, a01);
      a01 = __builtin_elementwise_fma(h0b, s1b, a01);
      a02 = __builtin_elementwise_fma(h0a, s2a, a02);
      a02 = __builtin_elementwise_fma(h0b, s2b, a02);
      a03 = __builtin_elementwise_fma(h0a, s3a, a03);
      a03 = __builtin_elementwise_fma(h0b, s3b, a03);
      a10 = __builtin_elementwise_fma(h1a, s0a, a10);
      a10 = __builtin_elementwise_fma(h1b, s0b, a10);
      a11 = __builtin_elementwise_fma(h1a, s1a, a11);
      a11 = __builtin_elementwise_fma(h1b, s1b, a11);
      a12 = __builtin_elementwise_fma(h1a, s2a, a12);
      a12 = __builtin_elementwise_fma(h1b, s2b, a12);
      a13 = __builtin_elementwise_fma(h1a, s3a, a13);
      a13 = __builtin_elementwise_fma(h1b, s3b, a13);
    }

    float s00 = a00.x + a00.y, s01 = a01.x + a01.y;
    float s02 = a02.x + a02.y, s03 = a03.x + a03.y;
    float s10 = a10.x + a10.y, s11 = a11.x + a11.y;
    float s12 = a12.x + a12.y, s13 = a13.x + a13.y;
    s00 = dpp_red8(s00); s01 = dpp_red8(s01);
    s02 = dpp_red8(s02); s03 = dpp_red8(s03);
    s10 = dpp_red8(s10); s11 = dpp_red8(s11);
    s12 = dpp_red8(s12); s13 = dpp_red8(s13);

    const float va = wc == 0 ? s00 : wc == 1 ? s01 : wc == 2 ? s02 : s03;
    const float vb = wc == 0 ? s10 : wc == 1 ? s11 : wc == 2 ? s12 : s13;
    rec_s[wr][c0 + wc] = (wr ? vb : va) + bmine;
    barrier_lds();

    // --- gate phase (first 256 threads) ---
    if (gateT) {
      const float xz = tof(xzc);
      const float xr = tof(xrc);
      const float xh = tof(xhc);
      const float rz = rec_s[grow][gu];
      const float rr = rec_s[grow][H_ + gu];
      const float rh = rec_s[grow][2 * H_ + gu];
      const float z = fsigmoid(xz + rz);
      const float r = fsigmoid(xr + rr);
      const float hh = ftanh(xh + r * rh);
      const float hold = hbuf[grow][gu];
      const float hn = z * hold + (1.f - z) * hh;
      hbuf[grow][gu] = hn;
      if constexpr (!LAST) {
        const size_t sidx =
            ((size_t)(b0 + grow) * T_ + t) * (2 * H_) + dir * H_ + gu;
        const unsigned short hi = f2bs(hn);
        seqH[sidx] = hi;
        seqL[sidx] = f2bs(hn - bs2f(hi));
      }
      xzc = xzn;
      xrc = xrn;
      xhc = xhn;
    }
    barrier_lds();
  }

  if constexpr (LAST) {
    if (gateT) fin[(size_t)(b0 + grow) * (2 * H_) + dir * H_ + gu] =
        hbuf[grow][gu];
  }
}

// ---------------------------------------------------------------------------
// Dense head: out[b] = sigmoid(fin[b][:] . Wd + bd)
// ---------------------------------------------------------------------------
__global__ void dense_kernel(const float* __restrict__ fin,
                             const float* __restrict__ Wd,
                             const float* __restrict__ bd,
                             float* __restrict__ out) {
  __shared__ float w[2 * H_];
  const int tid = threadIdx.x;
  w[tid] = Wd[tid];
  __syncthreads();
  float s = bd[0];
  const float* row = fin + tid * (2 * H_);
#pragma unroll 8
  for (int jj = 0; jj < 2 * H_; ++jj) s = fmaf(row[jj], w[jj], s);
  out[tid] = 1.f / (1.f + __expf(-s));
}

// ---------------------------------------------------------------------------
template <typename XT>
static void run_model(const float* x, const float* Ws, const float* Us,
                      const float* bs, const float* Wd, const float* bd,
                      float* out, char* ws, hipStream_t stream) {
  const size_t xpB = (size_t)2 * T_ * B_ * G_ * sizeof(XT);
  const size_t seqB = (size_t)B_ * T_ * 2 * H_ * 2;  // bf16 bits
  const size_t wtB = (size_t)2 * 768 * K_ * 2;
  XT* xp = (XT*)ws;
  ushort* sHA = (ushort*)(ws + xpB);
  ushort* sLA = (ushort*)(ws + xpB + seqB);
  ushort* sHB = (ushort*)(ws + xpB + 2 * seqB);
  ushort* sLB = (ushort*)(ws + xpB + 3 * seqB);
  ushort* WhiT = (ushort*)(ws + xpB + 4 * seqB);
  ushort* WloT = WhiT + (size_t)768 * K_;
  float* UT = (float*)(ws + xpB + 4 * seqB + wtB);
  float* fin = (float*)(ws + xpB + 4 * seqB + wtB + (size_t)2 * G_ * H_ * 4);

  convX_kernel<<<4096, 256, 0, stream>>>(x, sHB, sLB);

  const ushort* AHs[3] = {sHB, sHA, sHB};
  const ushort* ALs[3] = {sLB, sLA, sLB};
  ushort* oH[3] = {sHA, sHB, nullptr};
  ushort* oL[3] = {sLA, sLB, nullptr};

  for (int l = 0; l < 3; ++l) {
    const float* Wl = Ws + (size_t)l * 2 * K_ * G_;
    const float* bl = bs + (size_t)l * 4 * G_;
    const float* Ul = Us + (size_t)l * 2 * H_ * G_;
    convW_kernel<<<768, 256, 0, stream>>>(Wl, WhiT, WloT);
    convU_kernel<<<dim3(G_, 2), 128, 0, stream>>>(Ul, UT);
    gemm3_kernel<XT><<<dim3(M_ / 128, 6), 256, 0, stream>>>(
        AHs[l], ALs[l], WhiT, WloT, bl, xp);
    if (l < 2)
      rec_kernel<XT, false><<<dim3(B_ / 2, 2), 768, 0, stream>>>(
          xp, UT, bl, oH[l], oL[l], nullptr);
    else
      rec_kernel<XT, true><<<dim3(B_ / 2, 2), 768, 0, stream>>>(
          xp, UT, bl, nullptr, nullptr, fin);
  }
  dense_kernel<<<1, B_, 0, stream>>>(fin, Wd, bd, out);
}

extern "C" void kernel_launch(void* const* d_in, const int* in_sizes, int n_in,
                              void* d_out, int out_size, void* d_ws,
                              size_t ws_size, hipStream_t stream) {
  const float* x = (const float*)d_in[0];
  const float* Ws = (const float*)d_in[1];
  const float* Us = (const float*)d_in[2];
  const float* bs = (const float*)d_in[3];
  const float* Wd = (const float*)d_in[4];
  const float* bd = (const float*)d_in[5];
  float* out = (float*)d_out;
  char* ws = (char*)d_ws;

  const size_t seqB = (size_t)B_ * T_ * 2 * H_ * 2;
  const size_t wtB = (size_t)2 * 768 * K_ * 2;
  const size_t utB = (size_t)2 * G_ * H_ * 4;
  const size_t finB = (size_t)B_ * 2 * H_ * 4;
  const size_t xp32 = (size_t)2 * T_ * B_ * G_ * 4;
  const size_t tierA = xp32 + 4 * seqB + wtB + utB + finB;  // ~642 MiB
  if (ws_size >= tierA)
    run_model<float>(x, Ws, Us, bs, Wd, bd, out, ws, stream);
  else
    run_model<bf16>(x, Ws, Us, bs, Wd, bd, out, ws, stream);
}

// Round 11
// 2370.844 us; speedup vs baseline: 1.1158x; 1.1158x over previous
//
#include <hip/hip_runtime.h>
#include <hip/hip_bf16.h>

#define DEV __device__ __forceinline__

constexpr int B_ = 256;   // batch
constexpr int T_ = 512;   // time
constexpr int H_ = 128;   // GRU units
constexpr int K_ = 256;   // input dim per layer (D = 2H = 256 for all layers)
constexpr int G_ = 384;   // 3H
constexpr int M_ = B_ * T_;
constexpr int LDSROW = 72;  // ushorts per LDS tile row (64 data + 8 pad)

using bf16 = __hip_bfloat16;
typedef short bf16x8 __attribute__((ext_vector_type(8)));
typedef float f32x4 __attribute__((ext_vector_type(4)));
typedef float f32x2 __attribute__((ext_vector_type(2)));

DEV float tof(float x) { return x; }
DEV float tof(bf16 x) { return __bfloat162float(x); }
DEV void stor(float* p, float v) { *p = v; }
DEV void stor(bf16* p, float v) { *p = __float2bfloat16(v); }

// float -> bf16 bits, round-to-nearest-even
DEV unsigned short f2bs(float f) {
  union { float f; unsigned u; } v;
  v.f = f;
  unsigned r = (v.u + 0x7FFFu + ((v.u >> 16) & 1u)) >> 16;
  return (unsigned short)r;
}
DEV float bs2f(unsigned short s) {
  union { unsigned u; float f; } v;
  v.u = ((unsigned)s) << 16;
  return v.f;
}

DEV float fsigmoid(float x) { return 1.f / (1.f + __expf(-x)); }
DEV float ftanh(float x) {
  x = fminf(20.f, fmaxf(-20.f, x));
  float e = __expf(-2.f * x);
  return (1.f - e) / (1.f + e);
}

// Barrier draining only LDS traffic (lgkmcnt), not global loads/stores.
DEV void barrier_lds() {
  asm volatile("s_waitcnt lgkmcnt(0)\n\ts_barrier" ::: "memory");
}

DEV f32x4 mfma16(bf16x8 a, bf16x8 b, f32x4 c) {
  return __builtin_amdgcn_mfma_f32_16x16x32_bf16(a, b, c, 0, 0, 0);
}

// Butterfly sum over 8-lane groups on the VALU pipe (DPP): masks {1,2,7} =
// quad_perm[1,0,3,2]=0xB1, quad_perm[2,3,0,1]=0x4E, row_half_mirror=0x141.
DEV float dpp_red8(float x) {
  int t;
  t = __builtin_amdgcn_update_dpp(0, __float_as_int(x), 0xB1, 0xF, 0xF, true);
  x += __int_as_float(t);
  t = __builtin_amdgcn_update_dpp(0, __float_as_int(x), 0x4E, 0xF, 0xF, true);
  x += __int_as_float(t);
  t = __builtin_amdgcn_update_dpp(0, __float_as_int(x), 0x141, 0xF, 0xF, true);
  x += __int_as_float(t);
  return x;
}

// Load 4 float4s (one U column's 64-float k-run quarter-strided) via VOLATILE
// asm: volatile asm results cannot be rematerialized, so the register
// allocator MUST keep them live in VGPRs for the whole kernel (the compiler
// has been silently reloading U from L2 every step in R4-R9 — 25.7 GB/dispatch
// = the measured L2-BW wall).
DEV void ldU16(const float* p, f32x4& a, f32x4& b, f32x4& c, f32x4& d) {
  asm volatile(
      "global_load_dwordx4 %0, %4, off\n\t"
      "global_load_dwordx4 %1, %4, off offset:128\n\t"
      "global_load_dwordx4 %2, %4, off offset:256\n\t"
      "global_load_dwordx4 %3, %4, off offset:384"
      : "=v"(a), "=v"(b), "=v"(c), "=v"(d)
      : "v"(p));
}

// ---------------------------------------------------------------------------
// convX: split fp32 x[M,256] into bf16 hi/lo arrays (layer-0 GEMM input).
// ---------------------------------------------------------------------------
__global__ __launch_bounds__(256) void convX_kernel(
    const float* __restrict__ x, ushort* __restrict__ hiA,
    ushort* __restrict__ loA) {
  const int n4 = M_ * K_ / 4;
  for (int idx = blockIdx.x * blockDim.x + threadIdx.x; idx < n4;
       idx += gridDim.x * blockDim.x) {
    float4 v = ((const float4*)x)[idx];
    ushort4 h, l;
    h.x = f2bs(v.x); l.x = f2bs(v.x - bs2f(h.x));
    h.y = f2bs(v.y); l.y = f2bs(v.y - bs2f(h.y));
    h.z = f2bs(v.z); l.z = f2bs(v.z - bs2f(h.z));
    h.w = f2bs(v.w); l.w = f2bs(v.w - bs2f(h.w));
    ((ushort4*)hiA)[idx] = h;
    ((ushort4*)loA)[idx] = l;
  }
}

// ---------------------------------------------------------------------------
// convW: W[dir][256][384] fp32 -> W^T hi/lo bf16 [768 ncol][256 k].
// ---------------------------------------------------------------------------
__global__ __launch_bounds__(256) void convW_kernel(
    const float* __restrict__ W, ushort* __restrict__ WhiT,
    ushort* __restrict__ WloT) {
  const int ncol = blockIdx.x;           // 0..767
  const int dir = ncol / G_, j = ncol % G_;
  const int k = threadIdx.x;             // 0..255
  const float f = W[((size_t)dir * K_ + k) * G_ + j];
  const unsigned short hi = f2bs(f);
  WhiT[(size_t)ncol * K_ + k] = hi;
  WloT[(size_t)ncol * K_ + k] = f2bs(f - bs2f(hi));
}

// ---------------------------------------------------------------------------
// convU: U[dir][128][384] fp32 -> UT[dir][384 col][128 k] (transposed),
// so the rec kernel's per-column k-runs are contiguous dwordx4 loads.
// ---------------------------------------------------------------------------
__global__ __launch_bounds__(128) void convU_kernel(
    const float* __restrict__ U, float* __restrict__ UT) {
  const int col = blockIdx.x;   // 0..383
  const int dir = blockIdx.y;
  const int k = threadIdx.x;    // 0..127
  UT[((size_t)dir * G_ + col) * H_ + k] =
      U[(size_t)dir * H_ * G_ + (size_t)k * G_ + col];
}

// ---------------------------------------------------------------------------
// gemm3: C[M,768] = A[M,256] @ W^T' + bias, bf16 hi/lo 3-term split MFMA.
// ---------------------------------------------------------------------------
template <typename XT>
__global__ __launch_bounds__(256, 2) void gemm3_kernel(
    const ushort* __restrict__ Ahi, const ushort* __restrict__ Alo,
    const ushort* __restrict__ WhiT, const ushort* __restrict__ WloT,
    const float* __restrict__ bbias, XT* __restrict__ xp) {
  const int m0 = blockIdx.x * 128;
  const int n0 = blockIdx.y * 128;
  const int tid = threadIdx.x;
  const int w = tid >> 6, lane = tid & 63;
  const int wm = w >> 1, wn = w & 1;
  const int col = lane & 15, quad = lane >> 4;

  __shared__ __align__(16) ushort AH[128 * LDSROW];
  __shared__ __align__(16) ushort AL[128 * LDSROW];
  __shared__ __align__(16) ushort BH[128 * LDSROW];
  __shared__ __align__(16) ushort BL[128 * LDSROW];

  f32x4 acc[4][4];
#pragma unroll
  for (int i = 0; i < 4; ++i)
#pragma unroll
    for (int n = 0; n < 4; ++n) acc[i][n] = (f32x4){0.f, 0.f, 0.f, 0.f};

  const ushort* gsrc = (w == 0) ? Ahi : (w == 1) ? Alo : (w == 2) ? WhiT : WloT;
  ushort* lds = (w == 0) ? AH : (w == 1) ? AL : (w == 2) ? BH : BL;
  const int rbase = (w < 2) ? m0 : n0;

  for (int kb = 0; kb < K_; kb += 64) {
#pragma unroll
    for (int q = 0; q < 16; ++q) {
      const int slot = q * 64 + lane;
      const int r = slot >> 3, s = slot & 7;
      bf16x8 v = *(const bf16x8*)(gsrc + (size_t)(rbase + r) * K_ + kb + s * 8);
      *(bf16x8*)&lds[r * LDSROW + s * 8] = v;
    }
    __syncthreads();
#pragma unroll
    for (int z = 0; z < 2; ++z) {
      const int cc8 = (z * 4 + quad) * 8;
      bf16x8 ah[4], al[4], bh[4], bl[4];
#pragma unroll
      for (int i = 0; i < 4; ++i) {
        const int row = wm * 64 + i * 16 + col;
        ah[i] = *(const bf16x8*)&AH[row * LDSROW + cc8];
        al[i] = *(const bf16x8*)&AL[row * LDSROW + cc8];
      }
#pragma unroll
      for (int n = 0; n < 4; ++n) {
        const int row = wn * 64 + n * 16 + col;
        bh[n] = *(const bf16x8*)&BH[row * LDSROW + cc8];
        bl[n] = *(const bf16x8*)&BL[row * LDSROW + cc8];
      }
#pragma unroll
      for (int i = 0; i < 4; ++i)
#pragma unroll
        for (int n = 0; n < 4; ++n) {
          acc[i][n] = mfma16(ah[i], bh[n], acc[i][n]);
          acc[i][n] = mfma16(al[i], bh[n], acc[i][n]);
          acc[i][n] = mfma16(ah[i], bl[n], acc[i][n]);
        }
    }
    __syncthreads();
  }

  const int dir = (n0 >= G_) ? 1 : 0;
#pragma unroll
  for (int n = 0; n < 4; ++n) {
    const int ncol = n0 + wn * 64 + n * 16 + col;
    const int g = ncol - dir * G_;
    const float bv = bbias[dir * 2 * G_ + g];
#pragma unroll
    for (int i = 0; i < 4; ++i) {
      const int mb = m0 + wm * 64 + i * 16 + quad * 4;
#pragma unroll
      for (int r = 0; r < 4; ++r) {
        const int m = mb + r;
        const int bb = m >> 9;          // T_ = 512
        const int t = m & (T_ - 1);
        stor(xp + ((size_t)(dir * T_ + t) * B_ + bb) * G_ + g,
             acc[i][n][r] + bv);
      }
    }
  }
}

// ---------------------------------------------------------------------------
// Recurrence (R9 structure + asm-volatile-pinned U). Grid (128, 2):
// 2 batch rows/block, 768 threads. Thread (cg=tid>>3, kc=tid&7) computes
// 4 columns [4cg,4cg+4) over k-chunks {32i+4kc..+4 : i<4}: 8 ds_read_b128,
// 64 v_pk_fma_f32, DPP 8-lane reduce. U: 16 f32x4 loaded ONCE by volatile
// asm global_load_dwordx4 from UT[col][128] — non-rematerializable, so they
// stay in VGPRs (launch_bounds(768,3) budget ~170; need ~125).
// ---------------------------------------------------------------------------
template <typename XT, bool LAST>
__global__ __launch_bounds__(768, 3) void rec_kernel(
    const XT* __restrict__ xp, const float* UTbase,
    const float* __restrict__ bbase, ushort* __restrict__ seqH,
    ushort* __restrict__ seqL, float* __restrict__ fin) {
  const int dir = blockIdx.y;
  const float* UT = UTbase + (size_t)dir * G_ * H_;   // [col][128]
  const float* bh = bbase + dir * (2 * G_) + G_;
  const int b0 = blockIdx.x * 2;
  const int tid = threadIdx.x;
  const int kc = tid & 7;        // k-chunk selector
  const int cg = tid >> 3;       // column group 0..95
  const int kc4 = kc * 4;
  const int c0 = cg * 4;

  __shared__ __align__(16) float hbuf[2][H_];
  __shared__ float rec_s[2][G_];

  // U fragments: u{c}{i} = UT[c0+c][i*32 + kc4 .. +4), pinned via asm.
  f32x4 u00, u01, u02, u03, u10, u11, u12, u13;
  f32x4 u20, u21, u22, u23, u30, u31, u32, u33;
  ldU16(UT + (size_t)(c0 + 0) * H_ + kc4, u00, u01, u02, u03);
  ldU16(UT + (size_t)(c0 + 1) * H_ + kc4, u10, u11, u12, u13);
  ldU16(UT + (size_t)(c0 + 2) * H_ + kc4, u20, u21, u22, u23);
  ldU16(UT + (size_t)(c0 + 3) * H_ + kc4, u30, u31, u32, u33);
  asm volatile("s_waitcnt vmcnt(0)" ::: "memory");

  const int wc = kc & 3, wr = kc >> 2;     // this thread's rec_s write slot
  const float bmine = bh[c0 + wc];

  const int grow = tid >> 7;        // gate-phase row (tid < 256)
  const int gu = tid & (H_ - 1);    // gate-phase unit
  const bool gateT = tid < 2 * H_;

  if (gateT) hbuf[grow][gu] = 0.f;

  const XT* xbase = xp + (size_t)(dir * T_) * B_ * G_;

  XT xzc{}, xrc{}, xhc{};
  {
    const int t0 = dir ? (T_ - 1) : 0;
    if (gateT) {
      const XT* xr_ = xbase + ((size_t)t0 * B_ + b0 + grow) * G_ + gu;
      xzc = xr_[0];
      xrc = xr_[H_];
      xhc = xr_[2 * H_];
    }
  }
  barrier_lds();

  for (int it = 0; it < T_; ++it) {
    const int t = dir ? (T_ - 1 - it) : it;

    // --- prefetch xp for step it+1 (hidden under the dot phase) ---
    XT xzn = xzc, xrn = xrc, xhn = xhc;
    if (gateT && (it + 1 < T_)) {
      const int tn = dir ? (t - 1) : (t + 1);
      const XT* xr_ = xbase + ((size_t)tn * B_ + b0 + grow) * G_ + gu;
      xzn = xr_[0];
      xrn = xr_[H_];
      xhn = xr_[2 * H_];
    }

    // --- dot phase: packed-fp32 FMA, 4 cols x 2 rows per thread ---
    f32x2 a00 = {0.f, 0.f}, a01 = {0.f, 0.f}, a02 = {0.f, 0.f}, a03 = {0.f, 0.f};
    f32x2 a10 = {0.f, 0.f}, a11 = {0.f, 0.f}, a12 = {0.f, 0.f}, a13 = {0.f, 0.f};
#define DOT_I(i, UA, UB, UC, UD)                                        \
  {                                                                     \
    float4 h0 = *(const float4*)&hbuf[0][(i) * 32 + kc4];               \
    float4 h1 = *(const float4*)&hbuf[1][(i) * 32 + kc4];               \
    f32x2 h0a = {h0.x, h0.y}, h0b = {h0.z, h0.w};                       \
    f32x2 h1a = {h1.x, h1.y}, h1b = {h1.z, h1.w};                       \
    f32x2 uAa = {UA.x, UA.y}, uAb = {UA.z, UA.w};                       \
    f32x2 uBa = {UB.x, UB.y}, uBb = {UB.z, UB.w};                       \
    f32x2 uCa = {UC.x, UC.y}, uCb = {UC.z, UC.w};                       \
    f32x2 uDa = {UD.x, UD.y}, uDb = {UD.z, UD.w};                       \
    a00 = __builtin_elementwise_fma(h0a, uAa, a00);                     \
    a00 = __builtin_elementwise_fma(h0b, uAb, a00);                     \
    a01 = __builtin_elementwise_fma(h0a, uBa, a01);                     \
    a01 = __builtin_elementwise_fma(h0b, uBb, a01);                     \
    a02 = __builtin_elementwise_fma(h0a, uCa, a02);                     \
    a02 = __builtin_elementwise_fma(h0b, uCb, a02);                     \
    a03 = __builtin_elementwise_fma(h0a, uDa, a03);                     \
    a03 = __builtin_elementwise_fma(h0b, uDb, a03);                     \
    a10 = __builtin_elementwise_fma(h1a, uAa, a10);                     \
    a10 = __builtin_elementwise_fma(h1b, uAb, a10);                     \
    a11 = __builtin_elementwise_fma(h1a, uBa, a11);                     \
    a11 = __builtin_elementwise_fma(h1b, uBb, a11);                     \
    a12 = __builtin_elementwise_fma(h1a, uCa, a12);                     \
    a12 = __builtin_elementwise_fma(h1b, uCb, a12);                     \
    a13 = __builtin_elementwise_fma(h1a, uDa, a13);                     \
    a13 = __builtin_elementwise_fma(h1b, uDb, a13);                     \
  }
    DOT_I(0, u00, u10, u20, u30)
    DOT_I(1, u01, u11, u21, u31)
    DOT_I(2, u02, u12, u22, u32)
    DOT_I(3, u03, u13, u23, u33)
#undef DOT_I

    float s00 = a00.x + a00.y, s01 = a01.x + a01.y;
    float s02 = a02.x + a02.y, s03 = a03.x + a03.y;
    float s10 = a10.x + a10.y, s11 = a11.x + a11.y;
    float s12 = a12.x + a12.y, s13 = a13.x + a13.y;
    s00 = dpp_red8(s00); s01 = dpp_red8(s01);
    s02 = dpp_red8(s02); s03 = dpp_red8(s03);
    s10 = dpp_red8(s10); s11 = dpp_red8(s11);
    s12 = dpp_red8(s12); s13 = dpp_red8(s13);

    const float va = wc == 0 ? s00 : wc == 1 ? s01 : wc == 2 ? s02 : s03;
    const float vb = wc == 0 ? s10 : wc == 1 ? s11 : wc == 2 ? s12 : s13;
    rec_s[wr][c0 + wc] = (wr ? vb : va) + bmine;
    barrier_lds();

    // --- gate phase (first 256 threads) ---
    if (gateT) {
      const float xz = tof(xzc);
      const float xr = tof(xrc);
      const float xh = tof(xhc);
      const float rz = rec_s[grow][gu];
      const float rr = rec_s[grow][H_ + gu];
      const float rh = rec_s[grow][2 * H_ + gu];
      const float z = fsigmoid(xz + rz);
      const float r = fsigmoid(xr + rr);
      const float hh = ftanh(xh + r * rh);
      const float hold = hbuf[grow][gu];
      const float hn = z * hold + (1.f - z) * hh;
      hbuf[grow][gu] = hn;
      if constexpr (!LAST) {
        const size_t sidx =
            ((size_t)(b0 + grow) * T_ + t) * (2 * H_) + dir * H_ + gu;
        const unsigned short hi = f2bs(hn);
        seqH[sidx] = hi;
        seqL[sidx] = f2bs(hn - bs2f(hi));
      }
      xzc = xzn;
      xrc = xrn;
      xhc = xhn;
    }
    barrier_lds();
  }

  if constexpr (LAST) {
    if (gateT) fin[(size_t)(b0 + grow) * (2 * H_) + dir * H_ + gu] =
        hbuf[grow][gu];
  }
}

// ---------------------------------------------------------------------------
// Dense head: out[b] = sigmoid(fin[b][:] . Wd + bd)
// ---------------------------------------------------------------------------
__global__ void dense_kernel(const float* __restrict__ fin,
                             const float* __restrict__ Wd,
                             const float* __restrict__ bd,
                             float* __restrict__ out) {
  __shared__ float w[2 * H_];
  const int tid = threadIdx.x;
  w[tid] = Wd[tid];
  __syncthreads();
  float s = bd[0];
  const float* row = fin + tid * (2 * H_);
#pragma unroll 8
  for (int jj = 0; jj < 2 * H_; ++jj) s = fmaf(row[jj], w[jj], s);
  out[tid] = 1.f / (1.f + __expf(-s));
}

// ---------------------------------------------------------------------------
template <typename XT>
static void run_model(const float* x, const float* Ws, const float* Us,
                      const float* bs, const float* Wd, const float* bd,
                      float* out, char* ws, hipStream_t stream) {
  const size_t xpB = (size_t)2 * T_ * B_ * G_ * sizeof(XT);
  const size_t seqB = (size_t)B_ * T_ * 2 * H_ * 2;  // bf16 bits
  const size_t wtB = (size_t)2 * 768 * K_ * 2;
  XT* xp = (XT*)ws;
  ushort* sHA = (ushort*)(ws + xpB);
  ushort* sLA = (ushort*)(ws + xpB + seqB);
  ushort* sHB = (ushort*)(ws + xpB + 2 * seqB);
  ushort* sLB = (ushort*)(ws + xpB + 3 * seqB);
  ushort* WhiT = (ushort*)(ws + xpB + 4 * seqB);
  ushort* WloT = WhiT + (size_t)768 * K_;
  float* UT = (float*)(ws + xpB + 4 * seqB + wtB);
  float* fin = (float*)(ws + xpB + 4 * seqB + wtB + (size_t)2 * G_ * H_ * 4);

  convX_kernel<<<4096, 256, 0, stream>>>(x, sHB, sLB);

  const ushort* AHs[3] = {sHB, sHA, sHB};
  const ushort* ALs[3] = {sLB, sLA, sLB};
  ushort* oH[3] = {sHA, sHB, nullptr};
  ushort* oL[3] = {sLA, sLB, nullptr};

  for (int l = 0; l < 3; ++l) {
    const float* Wl = Ws + (size_t)l * 2 * K_ * G_;
    const float* bl = bs + (size_t)l * 4 * G_;
    const float* Ul = Us + (size_t)l * 2 * H_ * G_;
    convW_kernel<<<768, 256, 0, stream>>>(Wl, WhiT, WloT);
    convU_kernel<<<dim3(G_, 2), 128, 0, stream>>>(Ul, UT);
    gemm3_kernel<XT><<<dim3(M_ / 128, 6), 256, 0, stream>>>(
        AHs[l], ALs[l], WhiT, WloT, bl, xp);
    if (l < 2)
      rec_kernel<XT, false><<<dim3(B_ / 2, 2), 768, 0, stream>>>(
          xp, UT, bl, oH[l], oL[l], nullptr);
    else
      rec_kernel<XT, true><<<dim3(B_ / 2, 2), 768, 0, stream>>>(
          xp, UT, bl, nullptr, nullptr, fin);
  }
  dense_kernel<<<1, B_, 0, stream>>>(fin, Wd, bd, out);
}

extern "C" void kernel_launch(void* const* d_in, const int* in_sizes, int n_in,
                              void* d_out, int out_size, void* d_ws,
                              size_t ws_size, hipStream_t stream) {
  const float* x = (const float*)d_in[0];
  const float* Ws = (const float*)d_in[1];
  const float* Us = (const float*)d_in[2];
  const float* bs = (const float*)d_in[3];
  const float* Wd = (const float*)d_in[4];
  const float* bd = (const float*)d_in[5];
  float* out = (float*)d_out;
  char* ws = (char*)d_ws;

  const size_t seqB = (size_t)B_ * T_ * 2 * H_ * 2;
  const size_t wtB = (size_t)2 * 768 * K_ * 2;
  const size_t utB = (size_t)2 * G_ * H_ * 4;
  const size_t finB = (size_t)B_ * 2 * H_ * 4;
  const size_t xp32 = (size_t)2 * T_ * B_ * G_ * 4;
  const size_t tierA = xp32 + 4 * seqB + wtB + utB + finB;  // ~642 MiB
  if (ws_size >= tierA)
    run_model<float>(x, Ws, Us, bs, Wd, bd, out, ws, stream);
  else
    run_model<bf16>(x, Ws, Us, bs, Wd, bd, out, ws, stream);
}